// Round 13
// baseline (748.399 us; speedup 1.0000x reference)
//
#include <hip/hip_runtime.h>
#include <math.h>

#define NN 50000
#define NE 600000
#define ADIM 75
#define HID 128
#define NLAYERS 4
#define NGRAPHS 128
#define BN_EPS 1e-5f
#define NNP 50048   // NN padded to 64-node blocks
#define NB64 (NNP / 64)   // 782 node-blocks

typedef short bhalf8 __attribute__((ext_vector_type(8)));
typedef float floatx4 __attribute__((ext_vector_type(4)));

__device__ __forceinline__ float sigm(float v) { return 1.0f / (1.0f + __expf(-v)); }
__device__ __forceinline__ float tanh_f(float v) {
    return 1.0f - 2.0f / (__expf(2.0f * v) + 1.0f);
}

// fp32 -> bf16 with round-to-nearest-even
__device__ __forceinline__ unsigned short f2bf(float f) {
    unsigned u = __builtin_bit_cast(unsigned, f);
    u = (u + 0x7FFFu + ((u >> 16) & 1u)) >> 16;
    return (unsigned short)u;
}
__device__ __forceinline__ float bf2f(unsigned short h) {
    return __builtin_bit_cast(float, ((unsigned)h) << 16);
}

// ---------------------------------------------------------------------------
// nf [NN x 75] fp32 -> nfb [NNP x 96] bf16 (K zero-padded 75->96)
// ---------------------------------------------------------------------------
__global__ __launch_bounds__(256) void k_nfb(
    const float* __restrict__ nf, unsigned short* __restrict__ nfb)
{
    int e = blockIdx.x * 256 + threadIdx.x;      // (n, k4): 50000*24
    if (e >= NN * 24) return;
    int n = e / 24, k4 = e - n * 24;
    ushort4 o;
    int k = k4 * 4;
    o.x = (k + 0 < ADIM) ? f2bf(nf[(size_t)n * ADIM + k + 0]) : 0;
    o.y = (k + 1 < ADIM) ? f2bf(nf[(size_t)n * ADIM + k + 1]) : 0;
    o.z = (k + 2 < ADIM) ? f2bf(nf[(size_t)n * ADIM + k + 2]) : 0;
    o.w = (k + 3 < ADIM) ? f2bf(nf[(size_t)n * ADIM + k + 3]) : 0;
    ((ushort4*)nfb)[(size_t)n * 24 + k4] = o;
}

// ---------------------------------------------------------------------------
// embW [128 x 75] -> bf16 B-fragments, K padded to 96:
//   layout [tc(8)][kb(3)][quad(4)][n(16)][j(8)], elem = W[tc*16+n][kb*32+quad*8+j]
// ---------------------------------------------------------------------------
__global__ __launch_bounds__(256) void k_wfrag_emb(
    const float* __restrict__ W, unsigned short* __restrict__ web)
{
    int e = blockIdx.x * 256 + threadIdx.x;      // 0..12287
    int j = e & 7, n = (e >> 3) & 15, quad = (e >> 7) & 3;
    int kb = (e >> 9) % 3, tc = e / 1536;
    int row = tc * 16 + n;
    int kk = kb * 32 + quad * 8 + j;
    web[e] = (kk < ADIM) ? f2bf(W[row * ADIM + kk]) : 0;
}

// ---------------------------------------------------------------------------
// MFMA embedding: y = relu(nf @ embW^T + b), BN sums.
// block 256 = 4 waves x 16 nodes (64 nodes/block); grid 782.
// ---------------------------------------------------------------------------
__global__ __launch_bounds__(256) void k_embed_m(
    const unsigned short* __restrict__ nfb, const unsigned short* __restrict__ web,
    const float* __restrict__ b, float* __restrict__ y,
    double* __restrict__ bnsum)
{
    __shared__ __align__(16) float hst[64 * 128];   // 32 KB h staging
    const int t = threadIdx.x;
    const int wave = t >> 6, lane = t & 63;
    const int col = lane & 15, quad = (lane >> 4) & 3;
    const int node0 = blockIdx.x * 64;

    const int anode = node0 + wave * 16 + col;
    bhalf8 afN[3];
#pragma unroll
    for (int kb = 0; kb < 3; kb++)
        afN[kb] = *(const bhalf8*)&nfb[(size_t)anode * 96 + kb * 32 + quad * 8];

    floatx4 acc[8];
#pragma unroll
    for (int tc = 0; tc < 8; tc++) {
        float bv = b[tc * 16 + col];
        acc[tc] = (floatx4){bv, bv, bv, bv};
    }

#pragma unroll
    for (int tc = 0; tc < 8; tc++) {
        bhalf8 bfr[3];
#pragma unroll
        for (int kb = 0; kb < 3; kb++)
            bfr[kb] = *(const bhalf8*)&web[((tc * 3 + kb) * 64 + lane) * 8];
#pragma unroll
        for (int kb = 0; kb < 3; kb++)
            acc[tc] = __builtin_amdgcn_mfma_f32_16x16x32_bf16(afN[kb], bfr[kb], acc[tc], 0, 0, 0);
    }

#pragma unroll
    for (int tc = 0; tc < 8; tc++)
#pragma unroll
        for (int e = 0; e < 4; e++) {
            float v = fmaxf(acc[tc][e], 0.0f);
            hst[(wave * 16 + quad * 4 + e) * 128 + tc * 16 + col] = v;
        }
    __syncthreads();

#pragma unroll
    for (int i = 0; i < 32; i++) {
        int idx = t + i * 256;
        if (node0 + (idx >> 7) < NN) y[(size_t)node0 * HID + idx] = hst[idx];
    }
    if (t < 128) {
        int count = NN - node0; if (count > 64) count = 64;
        float s = 0.f, s2 = 0.f;
        for (int m = 0; m < count; m++) { float v = hst[m * 128 + t]; s += v; s2 += v * v; }
        unsafeAtomicAdd(&bnsum[t], (double)s);
        unsafeAtomicAdd(&bnsum[128 + t], (double)s2);
    }
}

// ---------------------------------------------------------------------------
// BN finalize: scale/shift from double sums; re-zeros bnsum for next layer
// ---------------------------------------------------------------------------
__global__ void k_bnfin(double* __restrict__ bnsum, const float* __restrict__ g,
                        const float* __restrict__ beta, float* __restrict__ ss)
{
    int f = threadIdx.x;
    double mean = bnsum[f] / (double)NN;
    double var  = bnsum[128 + f] / (double)NN - mean * mean;
    float inv = rsqrtf((float)var + BN_EPS);
    float sc = g[f] * inv;
    ss[f] = sc;
    ss[128 + f] = beta[f] - (float)mean * sc;
    bnsum[f] = 0.0;
    bnsum[128 + f] = 0.0;
}

// ---------------------------------------------------------------------------
// Fused BN-apply + bf16 mirror + attention projections for the NEXT layer
// ---------------------------------------------------------------------------
__global__ __launch_bounds__(256) void k_bnx(
    const float* __restrict__ y, const float* __restrict__ ss,
    const float* __restrict__ attW, float* __restrict__ x,
    unsigned short* __restrict__ xb,
    float* __restrict__ as_, float* __restrict__ ad_)
{
    const int t = threadIdx.x;
    const int n = blockIdx.x * 4 + (t >> 6);
    const int lane = t & 63;
    float2 sc = ((const float2*)ss)[lane];
    float2 sh = ((const float2*)(ss + 128))[lane];
    float2 v = ((const float2*)y)[(size_t)n * 64 + lane];
    float2 xv;
    xv.x = v.x * sc.x + sh.x;
    xv.y = v.y * sc.y + sh.y;
    ((float2*)x)[(size_t)n * 64 + lane] = xv;
    unsigned pk = (unsigned)f2bf(xv.x) | ((unsigned)f2bf(xv.y) << 16);
    ((unsigned*)xb)[(size_t)n * 64 + lane] = pk;
    float2 aws = ((const float2*)attW)[lane];
    float2 awd = ((const float2*)(attW + 128))[lane];
    float pas = xv.x * aws.x + xv.y * aws.y;
    float pad = xv.x * awd.x + xv.y * awd.y;
#pragma unroll
    for (int msk = 32; msk >= 1; msk >>= 1) {
        pas += __shfl_xor(pas, msk);
        pad += __shfl_xor(pad, msk);
    }
    if (lane == 0) { as_[n] = pas; ad_[n] = pad; }
}

// ---------------------------------------------------------------------------
// Combined-weight precompute: Wc[l] = Wih[l] @ Wm[l], bmih[l] = Wih[l] @ bm[l]
// ---------------------------------------------------------------------------
__global__ __launch_bounds__(128) void k_wc(
    const float* __restrict__ Wih, const float* __restrict__ Wm,
    const float* __restrict__ bm, float* __restrict__ Wc, float* __restrict__ bmih)
{
    __shared__ float sw[128];
    __shared__ float red[128];
    const int b = blockIdx.x;
    const int l = b / 384, r = b - l * 384;
    const int t = threadIdx.x;
    const float* wihrow = Wih + ((size_t)l * 384 + r) * 128;
    sw[t] = wihrow[t];
    __syncthreads();
    const float* wm = Wm + (size_t)l * 128 * 128;
    float acc = 0.f;
#pragma unroll 8
    for (int k = 0; k < 128; k++) acc += sw[k] * wm[k * 128 + t];
    Wc[((size_t)l * 384 + r) * 128 + t] = acc;
    red[t] = sw[t] * bm[l * 128 + t];
    __syncthreads();
#pragma unroll
    for (int off = 64; off >= 1; off >>= 1) {
        if (t < off) red[t] += red[t + off];
        __syncthreads();
    }
    if (t == 0) bmih[l * 384 + r] = red[0];
}

// ---------------------------------------------------------------------------
// Convert Wc (fp32) and Whh to bf16 in MFMA B-fragment order:
//   layout [gate(3)][tc(8)][kb(4)][quad(4)][n(16)][j(8)] per layer-matrix
// ---------------------------------------------------------------------------
__global__ __launch_bounds__(256) void k_frag(
    const float* __restrict__ Wc, const float* __restrict__ Whh,
    unsigned short* __restrict__ wcb, unsigned short* __restrict__ whhb)
{
    const int b = blockIdx.x;
    const int mat = b / 192;
    const int e = (b - mat * 192) * 256 + threadIdx.x;   // 0..49151
    const int l = mat >> 1, which = mat & 1;
    const float* src = which ? (Whh + (size_t)l * 49152) : (Wc + (size_t)l * 49152);
    unsigned short* dst = which ? (whhb + (size_t)l * 49152) : (wcb + (size_t)l * 49152);
    int j = e & 7, n = (e >> 3) & 15, quad = (e >> 7) & 3;
    int kb = (e >> 9) & 3, tc = (e >> 11) & 7, g = (e >> 14) & 3;
    int row = g * 128 + tc * 16 + n;
    int kk = kb * 32 + quad * 8 + j;
    dst[e] = f2bf(src[row * 128 + kk]);
}

// ---------------------------------------------------------------------------
// CSR build: histogram, 3-kernel device-wide scan, scatter
// ---------------------------------------------------------------------------
__global__ __launch_bounds__(256) void k_count(const int* __restrict__ dst, int* __restrict__ cnt)
{
    int e = blockIdx.x * 256 + threadIdx.x;
    if (e < NE) atomicAdd(&cnt[dst[e]], 1);
}

#define SCAN_B 512
#define SCAN_G 98          // 98*512 = 50176 >= 50000

__global__ __launch_bounds__(SCAN_B) void k_scan1(
    const int* __restrict__ cnt, int* __restrict__ rowptr, int* __restrict__ bsum)
{
    __shared__ int s[SCAN_B];
    const int t = threadIdx.x;
    const int i = blockIdx.x * SCAN_B + t;
    int v = (i < NN) ? cnt[i] : 0;
    s[t] = v;
    __syncthreads();
#pragma unroll
    for (int off = 1; off < SCAN_B; off <<= 1) {
        int u = (t >= off) ? s[t - off] : 0;
        __syncthreads();
        s[t] += u;
        __syncthreads();
    }
    if (i < NN) rowptr[i] = s[t] - v;        // local exclusive
    if (t == SCAN_B - 1) bsum[blockIdx.x] = s[t];
}

__global__ __launch_bounds__(128) void k_scan2(int* __restrict__ bsum, int* __restrict__ rowptr)
{
    __shared__ int s[128];
    const int t = threadIdx.x;
    int v = (t < SCAN_G) ? bsum[t] : 0;
    s[t] = v;
    __syncthreads();
#pragma unroll
    for (int off = 1; off < 128; off <<= 1) {
        int u = (t >= off) ? s[t - off] : 0;
        __syncthreads();
        s[t] += u;
        __syncthreads();
    }
    if (t < SCAN_G) bsum[t] = s[t] - v;      // exclusive offsets
    if (t == 127) rowptr[NN] = s[127];       // grand total (= NE)
}

__global__ __launch_bounds__(SCAN_B) void k_scan3(
    int* __restrict__ rowptr, const int* __restrict__ bsum, int* __restrict__ wptr)
{
    const int i = blockIdx.x * SCAN_B + threadIdx.x;
    if (i < NN) {
        int v = rowptr[i] + bsum[blockIdx.x];
        rowptr[i] = v;
        wptr[i] = v;
    }
}

__global__ __launch_bounds__(256) void k_scatter(
    const int* __restrict__ src, const int* __restrict__ dst,
    int* __restrict__ wptr, int* __restrict__ ssrc)
{
    int e = blockIdx.x * 256 + threadIdx.x;
    if (e < NE) {
        int d = dst[e];
        int pos = atomicAdd(&wptr[d], 1);
        ssrc[pos] = src[e];
    }
}

// ---------------------------------------------------------------------------
// Gather-aggregate, BATCHED load issue (R10 win): read 8 edge ids at once,
// then 8 independent xb-row + as_ loads, then accumulate.
// block 256 = 8 nodes x 32 lanes (ushort4/lane); grid NN/8.
// ---------------------------------------------------------------------------
__global__ __launch_bounds__(256) void k_gather(
    const int* __restrict__ rowptr, const int* __restrict__ ssrc,
    const unsigned short* __restrict__ xb, const float* __restrict__ as_,
    const float* __restrict__ ad_, const float* __restrict__ attb, int l,
    unsigned short* __restrict__ aggxb, float* __restrict__ sumatt)
{
    const int t = threadIdx.x;
    const int n = blockIdx.x * 8 + (t >> 5);
    const int lane = t & 31;
    const int r0 = rowptr[n], r1 = rowptr[n + 1];
    const float adv = ad_[n] + attb[l];
    float4 acc = make_float4(0.f, 0.f, 0.f, 0.f);
    float satt = 0.f;
    for (int base = r0; base < r1; base += 8) {
        int ids[8];
#pragma unroll
        for (int k = 0; k < 8; k++) {
            int idx = base + k; if (idx >= r1) idx = r1 - 1;
            ids[k] = ssrc[idx];
        }
        ushort4 v[8];
        float a[8];
#pragma unroll
        for (int k = 0; k < 8; k++) {
            v[k] = ((const ushort4*)xb)[(size_t)ids[k] * 32 + lane];
            a[k] = as_[ids[k]];
        }
#pragma unroll
        for (int k = 0; k < 8; k++) {
            if (base + k < r1) {
                float att = sigm(a[k] + adv);
                acc.x += bf2f(v[k].x) * att; acc.y += bf2f(v[k].y) * att;
                acc.z += bf2f(v[k].z) * att; acc.w += bf2f(v[k].w) * att;
                satt += att;
            }
        }
    }
    ushort4 o;
    o.x = f2bf(acc.x); o.y = f2bf(acc.y); o.z = f2bf(acc.z); o.w = f2bf(acc.w);
    ((ushort4*)aggxb)[(size_t)n * 32 + lane] = o;
    if (lane == 0) sumatt[n] = satt;
}

// ---------------------------------------------------------------------------
// MFMA GRU, barrier-free K-loop, register-slim algebra.
// R13: amdgpu_waves_per_eu(4,4) — min=4 caps VGPR at 128 (vs natural 136),
// max=4 stops the allocator from over-shrinking (R11: launch_bounds(256,4)
// min-only let it target 8 waves/EU -> 64 VGPR -> scratch spills).
//  - gates r,z accumulate BOTH matmuls into ONE accumulator
//  - gate n: acc = afX@Whh + bh; acc = r*acc + bi + sa*bm; acc += afA@Wc
// NOTE (R8 lesson): do NOT split this grid along columns — A-traffic
// multiplies by the split factor (FETCH 13.6 -> 51.5 MB measured).
// ---------------------------------------------------------------------------
#define MMG(AF, ACC, BASE)                                                    \
    _Pragma("unroll")                                                         \
    for (int tc = 0; tc < 8; tc++) {                                          \
        bhalf8 bfr[4];                                                        \
        _Pragma("unroll")                                                     \
        for (int kb = 0; kb < 4; kb++)                                        \
            bfr[kb] = *(const bhalf8*)&(BASE)[((tc * 4 + kb) * 64 + lane) * 8]; \
        _Pragma("unroll")                                                     \
        for (int kb = 0; kb < 4; kb++)                                        \
            ACC[tc] = __builtin_amdgcn_mfma_f32_16x16x32_bf16(AF[kb], bfr[kb], ACC[tc], 0, 0, 0); \
    }

__global__ __launch_bounds__(256)
__attribute__((amdgpu_waves_per_eu(4, 4)))
void k_gru(
    const unsigned short* __restrict__ aggxb, const float* __restrict__ sumatt,
    const unsigned short* __restrict__ xb,
    const unsigned short* __restrict__ wcb, const float* __restrict__ bmih,
    const float* __restrict__ bih,
    const unsigned short* __restrict__ whhb, const float* __restrict__ bhh,
    float* __restrict__ y, double* __restrict__ bnsum)
{
    __shared__ __align__(16) float hst[64 * 128];   // 32 KB h staging
    const int t = threadIdx.x;
    const int wave = t >> 6, lane = t & 63;
    const int col = lane & 15, quad = (lane >> 4) & 3;
    const int node0 = blockIdx.x * 64;

    const int anode = node0 + wave * 16 + col;
    bhalf8 afA[4], afX[4];
#pragma unroll
    for (int kb = 0; kb < 4; kb++) {
        afA[kb] = *(const bhalf8*)&aggxb[(size_t)anode * HID + kb * 32 + quad * 8];
        afX[kb] = *(const bhalf8*)&xb[(size_t)anode * HID + kb * 32 + quad * 8];
    }
    float sa[4];
#pragma unroll
    for (int e = 0; e < 4; e++) sa[e] = sumatt[node0 + wave * 16 + quad * 4 + e];

    floatx4 accR[8], accN[8];

    // ===== gate r: merged accumulator (gi+gh) =====
#pragma unroll
    for (int tc = 0; tc < 8; tc++) {
        int f = 0 * 128 + tc * 16 + col;
        float b0 = bih[f] + bhh[f], bm = bmih[f];
        accR[tc] = (floatx4){b0 + sa[0] * bm, b0 + sa[1] * bm, b0 + sa[2] * bm, b0 + sa[3] * bm};
    }
    MMG(afA, accR, wcb + 0 * 16384);
    MMG(afX, accR, whhb + 0 * 16384);
#pragma unroll
    for (int tc = 0; tc < 8; tc++)
#pragma unroll
        for (int e = 0; e < 4; e++)
            accR[tc][e] = sigm(accR[tc][e]);          // accR now holds r

    // ===== gate n: acc = afX@Whh + bh; acc = r*acc + bi + sa*bm; acc += afA@Wc =====
#pragma unroll
    for (int tc = 0; tc < 8; tc++) {
        float bh = bhh[2 * 128 + tc * 16 + col];
        accN[tc] = (floatx4){bh, bh, bh, bh};
    }
    MMG(afX, accN, whhb + 2 * 16384);
#pragma unroll
    for (int tc = 0; tc < 8; tc++) {
        int f = 2 * 128 + tc * 16 + col;
        float bi = bih[f], bm = bmih[f];
#pragma unroll
        for (int e = 0; e < 4; e++)
            accN[tc][e] = accR[tc][e] * accN[tc][e] + bi + sa[e] * bm;
    }
    MMG(afA, accN, wcb + 2 * 16384);
#pragma unroll
    for (int tc = 0; tc < 8; tc++)
#pragma unroll
        for (int e = 0; e < 4; e++)
            accN[tc][e] = tanh_f(accN[tc][e]);        // accN now holds n

    // ===== gate z: merged accumulator (reuse accR) =====
#pragma unroll
    for (int tc = 0; tc < 8; tc++) {
        int f = 1 * 128 + tc * 16 + col;
        float b0 = bih[f] + bhh[f], bm = bmih[f];
        accR[tc] = (floatx4){b0 + sa[0] * bm, b0 + sa[1] * bm, b0 + sa[2] * bm, b0 + sa[3] * bm};
    }
    MMG(afA, accR, wcb + 1 * 16384);
    MMG(afX, accR, whhb + 1 * 16384);

    // ===== h = (1-z)*n + z*x, stage, write, BN sums =====
#pragma unroll
    for (int tc = 0; tc < 8; tc++) {
#pragma unroll
        for (int e = 0; e < 4; e++) {
            float z = sigm(accR[tc][e]);
            int nd = node0 + wave * 16 + quad * 4 + e;
            float xv = bf2f(xb[(size_t)nd * HID + tc * 16 + col]);
            float h = (1.0f - z) * accN[tc][e] + z * xv;
            hst[(wave * 16 + quad * 4 + e) * 128 + tc * 16 + col] = h;
        }
    }
    __syncthreads();

#pragma unroll
    for (int i = 0; i < 32; i++) {
        int idx = t + i * 256;
        if (node0 + (idx >> 7) < NN) y[(size_t)node0 * HID + idx] = hst[idx];
    }
    if (t < 128) {
        int count = NN - node0; if (count > 64) count = 64;
        float s = 0.f, s2 = 0.f;
        for (int m = 0; m < count; m++) { float v = hst[m * 128 + t]; s += v; s2 += v * v; }
        unsafeAtomicAdd(&bnsum[t], (double)s);
        unsafeAtomicAdd(&bnsum[128 + t], (double)s2);
    }
}

// ---------------------------------------------------------------------------
// Segmented sum-pool (batch_idx is SORTED)
// ---------------------------------------------------------------------------
__global__ __launch_bounds__(256) void k_pool(
    const float* __restrict__ x, const int* __restrict__ batch, float* __restrict__ gr)
{
    __shared__ int sb[256];
    const int t = threadIdx.x;
    const int nb = blockIdx.x * 256;
    int ld = nb + t; if (ld >= NN) ld = NN - 1;
    sb[t] = batch[ld];
    __syncthreads();
    const int s = t >> 7, f = t & 127;
    float acc = 0.f; int cur = -1;
    for (int i = s; i < 256; i += 2) {
        int n = nb + i;
        if (n >= NN) break;
        int g = sb[i];
        if (g != cur) {
            if (cur >= 0) unsafeAtomicAdd(&gr[(size_t)cur * HID + f], acc);
            acc = 0.f; cur = g;
        }
        acc += x[(size_t)n * HID + f];
    }
    if (cur >= 0) unsafeAtomicAdd(&gr[(size_t)cur * HID + f], acc);
}

// ---------------------------------------------------------------------------
// Readout: out[g] = relu(gr[g] @ W1^T + b1) @ W2^T + b2   (128 blocks x 64)
// ---------------------------------------------------------------------------
__global__ __launch_bounds__(64) void k_readout(
    const float* __restrict__ gr, const float* __restrict__ W1,
    const float* __restrict__ b1, const float* __restrict__ W2,
    const float* __restrict__ b2, float* __restrict__ out)
{
    const int g = blockIdx.x, j = threadIdx.x;
    float acc = b1[j];
    const float4* grow = (const float4*)&gr[g * HID];
    const float4* wrow = (const float4*)&W1[j * HID];
#pragma unroll
    for (int k4 = 0; k4 < 32; k4++) {
        float4 a = grow[k4], w = wrow[k4];
        acc += a.x * w.x + a.y * w.y + a.z * w.z + a.w * w.w;
    }
    float h = fmaxf(acc, 0.0f) * W2[j];
#pragma unroll
    for (int msk = 32; msk >= 1; msk >>= 1) h += __shfl_xor(h, msk);
    if (j == 0) out[g] = h + b2[0];
}

// ---------------------------------------------------------------------------
extern "C" void kernel_launch(void* const* d_in, const int* in_sizes, int n_in,
                              void* d_out, int out_size, void* d_ws, size_t ws_size,
                              hipStream_t stream)
{
    const float* nf    = (const float*)d_in[0];
    const int*   ei    = (const int*)d_in[1];
    const int*   batch = (const int*)d_in[2];
    const float* embW  = (const float*)d_in[3];
    const float* embb  = (const float*)d_in[4];
    const float* embg  = (const float*)d_in[5];
    const float* embbe = (const float*)d_in[6];
    const float* msgW  = (const float*)d_in[7];
    const float* msgb  = (const float*)d_in[8];
    const float* attW  = (const float*)d_in[9];
    const float* attb  = (const float*)d_in[10];
    const float* Wih   = (const float*)d_in[11];
    const float* bih   = (const float*)d_in[12];
    const float* Whh   = (const float*)d_in[13];
    const float* bhh   = (const float*)d_in[14];
    const float* bng   = (const float*)d_in[15];
    const float* bnb   = (const float*)d_in[16];
    const float* roW1  = (const float*)d_in[17];
    const float* rob1  = (const float*)d_in[18];
    const float* roW2  = (const float*)d_in[19];
    const float* rob2  = (const float*)d_in[20];
    const int* src = ei;
    const int* dst = ei + NE;
    float* out = (float*)d_out;

    // ---- workspace layout (all sections 16B-multiple) ----
    char* base = (char*)d_ws;
    const size_t NH = (size_t)NN * HID;      // 6.4M elements
    double* bnsum = (double*)base;           // 256 doubles = 2048 B
    float* x     = (float*)(base + 2048);    // fp32 node state
    float* y     = x + NH;                   // pre-BN state
    unsigned short* xb    = (unsigned short*)(y + NH);   // bf16 mirror of x
    unsigned short* aggxb = xb + NH;                     // bf16 gather output
    float* as_   = (float*)(aggxb + NH);
    float* ad_   = as_ + NN;
    float* sumatt= ad_ + NN;
    float* ss    = sumatt + NN;              // 256: scale|shift
    float* gr    = ss + 256;                 // 128*128
    float* Wc    = gr + NGRAPHS * HID;       // 4*384*128 fp32
    float* bmih  = Wc + 4 * 384 * 128;       // 4*384
    int* rowptr  = (int*)(bmih + 4 * 384);   // NN+4 (padded for alignment)
    int* wptr    = rowptr + NN + 4;          // NN
    int* cnt     = wptr + NN;                // NN
    int* bsum    = cnt + NN;                 // 128 (scan block totals)
    int* ssrc    = bsum + 128;               // NE
    unsigned short* wcb  = (unsigned short*)(ssrc + NE); // 4*49152 bf16 frags
    unsigned short* whhb = wcb + 4 * 49152;              // 4*49152 bf16 frags
    unsigned short* nfb  = whhb + 4 * 49152;             // NNP*96 bf16 padded nf
    unsigned short* web  = nfb + (size_t)NNP * 96;       // 12288 emb B-frags

    // ---- once-per-call precompute: weights (+bf16 frags), nf cast, CSR ----
    k_wc<<<4 * 384, 128, 0, stream>>>(Wih, msgW, msgb, Wc, bmih);
    k_frag<<<8 * 192, 256, 0, stream>>>(Wc, Whh, wcb, whhb);
    k_nfb<<<(NN * 24 + 255) / 256, 256, 0, stream>>>(nf, nfb);
    k_wfrag_emb<<<48, 256, 0, stream>>>(embW, web);
    hipMemsetAsync(cnt, 0, NN * sizeof(int), stream);
    k_count<<<(NE + 255) / 256, 256, 0, stream>>>(dst, cnt);
    k_scan1<<<SCAN_G, SCAN_B, 0, stream>>>(cnt, rowptr, bsum);
    k_scan2<<<1, 128, 0, stream>>>(bsum, rowptr);
    k_scan3<<<SCAN_G, SCAN_B, 0, stream>>>(rowptr, bsum, wptr);
    k_scatter<<<(NE + 255) / 256, 256, 0, stream>>>(src, dst, wptr, ssrc);

    // ---- MFMA embedding + BN + att-proj for layer 0 ----
    hipMemsetAsync(bnsum, 0, 256 * sizeof(double), stream);
    k_embed_m<<<NB64, 256, 0, stream>>>(nfb, web, embb, y, bnsum);
    k_bnfin<<<1, 128, 0, stream>>>(bnsum, embg, embbe, ss);   // also re-zeros bnsum
    k_bnx<<<NN / 4, 256, 0, stream>>>(y, ss, attW, x, xb, as_, ad_);

    for (int l = 0; l < NLAYERS; l++) {
        k_gather<<<NN / 8, 256, 0, stream>>>(rowptr, ssrc, xb, as_, ad_, attb, l, aggxb, sumatt);
        k_gru<<<NB64, 256, 0, stream>>>(
            aggxb, sumatt, xb,
            wcb + (size_t)l * 49152, bmih + (size_t)l * 384, bih + (size_t)l * 384,
            whhb + (size_t)l * 49152, bhh + (size_t)l * 384, y, bnsum);
        k_bnfin<<<1, 128, 0, stream>>>(bnsum, bng + (size_t)l * HID, bnb + (size_t)l * HID, ss);
        const float* attW_next = attW + (size_t)((l + 1 < NLAYERS) ? l + 1 : l) * 256;
        k_bnx<<<NN / 4, 256, 0, stream>>>(y, ss, attW_next, x, xb, as_, ad_);
    }

    hipMemsetAsync(gr, 0, NGRAPHS * HID * sizeof(float), stream);
    k_pool<<<(NN + 255) / 256, 256, 0, stream>>>(x, batch, gr);
    k_readout<<<NGRAPHS, 64, 0, stream>>>(gr, roW1, rob1, roW2, rob2, out);
}

// Round 14
// 696.683 us; speedup vs baseline: 1.0742x; 1.0742x over previous
//
#include <hip/hip_runtime.h>
#include <math.h>

#define NN 50000
#define NE 600000
#define ADIM 75
#define HID 128
#define NLAYERS 4
#define NGRAPHS 128
#define BN_EPS 1e-5f
#define NNP 50048   // NN padded to 64-node blocks
#define NB64 (NNP / 64)   // 782 node-blocks

typedef short bhalf8 __attribute__((ext_vector_type(8)));
typedef float floatx4 __attribute__((ext_vector_type(4)));

__device__ __forceinline__ float sigm(float v) { return 1.0f / (1.0f + __expf(-v)); }
__device__ __forceinline__ float tanh_f(float v) {
    return 1.0f - 2.0f / (__expf(2.0f * v) + 1.0f);
}

// fp32 -> bf16 with round-to-nearest-even
__device__ __forceinline__ unsigned short f2bf(float f) {
    unsigned u = __builtin_bit_cast(unsigned, f);
    u = (u + 0x7FFFu + ((u >> 16) & 1u)) >> 16;
    return (unsigned short)u;
}
__device__ __forceinline__ float bf2f(unsigned short h) {
    return __builtin_bit_cast(float, ((unsigned)h) << 16);
}

// ---------------------------------------------------------------------------
// nf [NN x 75] fp32 -> nfb [NNP x 96] bf16 (K zero-padded 75->96)
// ---------------------------------------------------------------------------
__global__ __launch_bounds__(256) void k_nfb(
    const float* __restrict__ nf, unsigned short* __restrict__ nfb)
{
    int e = blockIdx.x * 256 + threadIdx.x;      // (n, k4): 50000*24
    if (e >= NN * 24) return;
    int n = e / 24, k4 = e - n * 24;
    ushort4 o;
    int k = k4 * 4;
    o.x = (k + 0 < ADIM) ? f2bf(nf[(size_t)n * ADIM + k + 0]) : 0;
    o.y = (k + 1 < ADIM) ? f2bf(nf[(size_t)n * ADIM + k + 1]) : 0;
    o.z = (k + 2 < ADIM) ? f2bf(nf[(size_t)n * ADIM + k + 2]) : 0;
    o.w = (k + 3 < ADIM) ? f2bf(nf[(size_t)n * ADIM + k + 3]) : 0;
    ((ushort4*)nfb)[(size_t)n * 24 + k4] = o;
}

// ---------------------------------------------------------------------------
// embW [128 x 75] -> bf16 B-fragments, K padded to 96:
//   layout [tc(8)][kb(3)][quad(4)][n(16)][j(8)], elem = W[tc*16+n][kb*32+quad*8+j]
// ---------------------------------------------------------------------------
__global__ __launch_bounds__(256) void k_wfrag_emb(
    const float* __restrict__ W, unsigned short* __restrict__ web)
{
    int e = blockIdx.x * 256 + threadIdx.x;      // 0..12287
    int j = e & 7, n = (e >> 3) & 15, quad = (e >> 7) & 3;
    int kb = (e >> 9) % 3, tc = e / 1536;
    int row = tc * 16 + n;
    int kk = kb * 32 + quad * 8 + j;
    web[e] = (kk < ADIM) ? f2bf(W[row * ADIM + kk]) : 0;
}

// ---------------------------------------------------------------------------
// MFMA embedding: y = relu(nf @ embW^T + b), BN sums.
// block 256 = 4 waves x 16 nodes (64 nodes/block); grid 782.
// ---------------------------------------------------------------------------
__global__ __launch_bounds__(256) void k_embed_m(
    const unsigned short* __restrict__ nfb, const unsigned short* __restrict__ web,
    const float* __restrict__ b, float* __restrict__ y,
    double* __restrict__ bnsum)
{
    __shared__ __align__(16) float hst[64 * 128];   // 32 KB h staging
    const int t = threadIdx.x;
    const int wave = t >> 6, lane = t & 63;
    const int col = lane & 15, quad = (lane >> 4) & 3;
    const int node0 = blockIdx.x * 64;

    const int anode = node0 + wave * 16 + col;
    bhalf8 afN[3];
#pragma unroll
    for (int kb = 0; kb < 3; kb++)
        afN[kb] = *(const bhalf8*)&nfb[(size_t)anode * 96 + kb * 32 + quad * 8];

    floatx4 acc[8];
#pragma unroll
    for (int tc = 0; tc < 8; tc++) {
        float bv = b[tc * 16 + col];
        acc[tc] = (floatx4){bv, bv, bv, bv};
    }

#pragma unroll
    for (int tc = 0; tc < 8; tc++) {
        bhalf8 bfr[3];
#pragma unroll
        for (int kb = 0; kb < 3; kb++)
            bfr[kb] = *(const bhalf8*)&web[((tc * 3 + kb) * 64 + lane) * 8];
#pragma unroll
        for (int kb = 0; kb < 3; kb++)
            acc[tc] = __builtin_amdgcn_mfma_f32_16x16x32_bf16(afN[kb], bfr[kb], acc[tc], 0, 0, 0);
    }

#pragma unroll
    for (int tc = 0; tc < 8; tc++)
#pragma unroll
        for (int e = 0; e < 4; e++) {
            float v = fmaxf(acc[tc][e], 0.0f);
            hst[(wave * 16 + quad * 4 + e) * 128 + tc * 16 + col] = v;
        }
    __syncthreads();

#pragma unroll
    for (int i = 0; i < 32; i++) {
        int idx = t + i * 256;
        if (node0 + (idx >> 7) < NN) y[(size_t)node0 * HID + idx] = hst[idx];
    }
    if (t < 128) {
        int count = NN - node0; if (count > 64) count = 64;
        float s = 0.f, s2 = 0.f;
        for (int m = 0; m < count; m++) { float v = hst[m * 128 + t]; s += v; s2 += v * v; }
        unsafeAtomicAdd(&bnsum[t], (double)s);
        unsafeAtomicAdd(&bnsum[128 + t], (double)s2);
    }
}

// ---------------------------------------------------------------------------
// BN finalize: scale/shift from double sums; re-zeros bnsum for next layer
// ---------------------------------------------------------------------------
__global__ void k_bnfin(double* __restrict__ bnsum, const float* __restrict__ g,
                        const float* __restrict__ beta, float* __restrict__ ss)
{
    int f = threadIdx.x;
    double mean = bnsum[f] / (double)NN;
    double var  = bnsum[128 + f] / (double)NN - mean * mean;
    float inv = rsqrtf((float)var + BN_EPS);
    float sc = g[f] * inv;
    ss[f] = sc;
    ss[128 + f] = beta[f] - (float)mean * sc;
    bnsum[f] = 0.0;
    bnsum[128 + f] = 0.0;
}

// ---------------------------------------------------------------------------
// Fused BN-apply + bf16 mirror + attention projections for the NEXT layer.
// R14: fp32 x eliminated — only xb (bf16) is written; k_pool reads xb.
// Saves 25.6 MB of stores per call (x was only consumed by k_pool).
// ---------------------------------------------------------------------------
__global__ __launch_bounds__(256) void k_bnx(
    const float* __restrict__ y, const float* __restrict__ ss,
    const float* __restrict__ attW,
    unsigned short* __restrict__ xb,
    float* __restrict__ as_, float* __restrict__ ad_)
{
    const int t = threadIdx.x;
    const int n = blockIdx.x * 4 + (t >> 6);
    const int lane = t & 63;
    float2 sc = ((const float2*)ss)[lane];
    float2 sh = ((const float2*)(ss + 128))[lane];
    float2 v = ((const float2*)y)[(size_t)n * 64 + lane];
    float2 xv;
    xv.x = v.x * sc.x + sh.x;
    xv.y = v.y * sc.y + sh.y;
    unsigned pk = (unsigned)f2bf(xv.x) | ((unsigned)f2bf(xv.y) << 16);
    ((unsigned*)xb)[(size_t)n * 64 + lane] = pk;
    float2 aws = ((const float2*)attW)[lane];
    float2 awd = ((const float2*)(attW + 128))[lane];
    float pas = xv.x * aws.x + xv.y * aws.y;
    float pad = xv.x * awd.x + xv.y * awd.y;
#pragma unroll
    for (int msk = 32; msk >= 1; msk >>= 1) {
        pas += __shfl_xor(pas, msk);
        pad += __shfl_xor(pad, msk);
    }
    if (lane == 0) { as_[n] = pas; ad_[n] = pad; }
}

// ---------------------------------------------------------------------------
// Combined-weight precompute: Wc[l] = Wih[l] @ Wm[l], bmih[l] = Wih[l] @ bm[l]
// ---------------------------------------------------------------------------
__global__ __launch_bounds__(128) void k_wc(
    const float* __restrict__ Wih, const float* __restrict__ Wm,
    const float* __restrict__ bm, float* __restrict__ Wc, float* __restrict__ bmih)
{
    __shared__ float sw[128];
    __shared__ float red[128];
    const int b = blockIdx.x;
    const int l = b / 384, r = b - l * 384;
    const int t = threadIdx.x;
    const float* wihrow = Wih + ((size_t)l * 384 + r) * 128;
    sw[t] = wihrow[t];
    __syncthreads();
    const float* wm = Wm + (size_t)l * 128 * 128;
    float acc = 0.f;
#pragma unroll 8
    for (int k = 0; k < 128; k++) acc += sw[k] * wm[k * 128 + t];
    Wc[((size_t)l * 384 + r) * 128 + t] = acc;
    red[t] = sw[t] * bm[l * 128 + t];
    __syncthreads();
#pragma unroll
    for (int off = 64; off >= 1; off >>= 1) {
        if (t < off) red[t] += red[t + off];
        __syncthreads();
    }
    if (t == 0) bmih[l * 384 + r] = red[0];
}

// ---------------------------------------------------------------------------
// Convert Wc (fp32) and Whh to bf16 in MFMA B-fragment order:
//   layout [gate(3)][tc(8)][kb(4)][quad(4)][n(16)][j(8)] per layer-matrix
// ---------------------------------------------------------------------------
__global__ __launch_bounds__(256) void k_frag(
    const float* __restrict__ Wc, const float* __restrict__ Whh,
    unsigned short* __restrict__ wcb, unsigned short* __restrict__ whhb)
{
    const int b = blockIdx.x;
    const int mat = b / 192;
    const int e = (b - mat * 192) * 256 + threadIdx.x;   // 0..49151
    const int l = mat >> 1, which = mat & 1;
    const float* src = which ? (Whh + (size_t)l * 49152) : (Wc + (size_t)l * 49152);
    unsigned short* dst = which ? (whhb + (size_t)l * 49152) : (wcb + (size_t)l * 49152);
    int j = e & 7, n = (e >> 3) & 15, quad = (e >> 7) & 3;
    int kb = (e >> 9) & 3, tc = (e >> 11) & 7, g = (e >> 14) & 3;
    int row = g * 128 + tc * 16 + n;
    int kk = kb * 32 + quad * 8 + j;
    dst[e] = f2bf(src[row * 128 + kk]);
}

// ---------------------------------------------------------------------------
// CSR build: histogram, 3-kernel device-wide scan, scatter
// ---------------------------------------------------------------------------
__global__ __launch_bounds__(256) void k_count(const int* __restrict__ dst, int* __restrict__ cnt)
{
    int e = blockIdx.x * 256 + threadIdx.x;
    if (e < NE) atomicAdd(&cnt[dst[e]], 1);
}

#define SCAN_B 512
#define SCAN_G 98          // 98*512 = 50176 >= 50000

__global__ __launch_bounds__(SCAN_B) void k_scan1(
    const int* __restrict__ cnt, int* __restrict__ rowptr, int* __restrict__ bsum)
{
    __shared__ int s[SCAN_B];
    const int t = threadIdx.x;
    const int i = blockIdx.x * SCAN_B + t;
    int v = (i < NN) ? cnt[i] : 0;
    s[t] = v;
    __syncthreads();
#pragma unroll
    for (int off = 1; off < SCAN_B; off <<= 1) {
        int u = (t >= off) ? s[t - off] : 0;
        __syncthreads();
        s[t] += u;
        __syncthreads();
    }
    if (i < NN) rowptr[i] = s[t] - v;        // local exclusive
    if (t == SCAN_B - 1) bsum[blockIdx.x] = s[t];
}

__global__ __launch_bounds__(128) void k_scan2(int* __restrict__ bsum, int* __restrict__ rowptr)
{
    __shared__ int s[128];
    const int t = threadIdx.x;
    int v = (t < SCAN_G) ? bsum[t] : 0;
    s[t] = v;
    __syncthreads();
#pragma unroll
    for (int off = 1; off < 128; off <<= 1) {
        int u = (t >= off) ? s[t - off] : 0;
        __syncthreads();
        s[t] += u;
        __syncthreads();
    }
    if (t < SCAN_G) bsum[t] = s[t] - v;      // exclusive offsets
    if (t == 127) rowptr[NN] = s[127];       // grand total (= NE)
}

__global__ __launch_bounds__(SCAN_B) void k_scan3(
    int* __restrict__ rowptr, const int* __restrict__ bsum, int* __restrict__ wptr)
{
    const int i = blockIdx.x * SCAN_B + threadIdx.x;
    if (i < NN) {
        int v = rowptr[i] + bsum[blockIdx.x];
        rowptr[i] = v;
        wptr[i] = v;
    }
}

__global__ __launch_bounds__(256) void k_scatter(
    const int* __restrict__ src, const int* __restrict__ dst,
    int* __restrict__ wptr, int* __restrict__ ssrc)
{
    int e = blockIdx.x * 256 + threadIdx.x;
    if (e < NE) {
        int d = dst[e];
        int pos = atomicAdd(&wptr[d], 1);
        ssrc[pos] = src[e];
    }
}

// ---------------------------------------------------------------------------
// Gather-aggregate, BATCHED load issue (R10 win): read 8 edge ids at once,
// then 8 independent xb-row + as_ loads, then accumulate.
// block 256 = 8 nodes x 32 lanes (ushort4/lane); grid NN/8.
// ---------------------------------------------------------------------------
__global__ __launch_bounds__(256) void k_gather(
    const int* __restrict__ rowptr, const int* __restrict__ ssrc,
    const unsigned short* __restrict__ xb, const float* __restrict__ as_,
    const float* __restrict__ ad_, const float* __restrict__ attb, int l,
    unsigned short* __restrict__ aggxb, float* __restrict__ sumatt)
{
    const int t = threadIdx.x;
    const int n = blockIdx.x * 8 + (t >> 5);
    const int lane = t & 31;
    const int r0 = rowptr[n], r1 = rowptr[n + 1];
    const float adv = ad_[n] + attb[l];
    float4 acc = make_float4(0.f, 0.f, 0.f, 0.f);
    float satt = 0.f;
    for (int base = r0; base < r1; base += 8) {
        int ids[8];
#pragma unroll
        for (int k = 0; k < 8; k++) {
            int idx = base + k; if (idx >= r1) idx = r1 - 1;
            ids[k] = ssrc[idx];
        }
        ushort4 v[8];
        float a[8];
#pragma unroll
        for (int k = 0; k < 8; k++) {
            v[k] = ((const ushort4*)xb)[(size_t)ids[k] * 32 + lane];
            a[k] = as_[ids[k]];
        }
#pragma unroll
        for (int k = 0; k < 8; k++) {
            if (base + k < r1) {
                float att = sigm(a[k] + adv);
                acc.x += bf2f(v[k].x) * att; acc.y += bf2f(v[k].y) * att;
                acc.z += bf2f(v[k].z) * att; acc.w += bf2f(v[k].w) * att;
                satt += att;
            }
        }
    }
    ushort4 o;
    o.x = f2bf(acc.x); o.y = f2bf(acc.y); o.z = f2bf(acc.z); o.w = f2bf(acc.w);
    ((ushort4*)aggxb)[(size_t)n * 32 + lane] = o;
    if (lane == 0) sumatt[n] = satt;
}

// ---------------------------------------------------------------------------
// MFMA GRU, barrier-free K-loop, register-slim algebra (R12 best config).
// Plain launch_bounds(256): natural allocation 136 VGPR, no spills, 69 us.
// R11/R13 lesson: BOTH occupancy forcings (launch_bounds(256,4) and
// amdgpu_waves_per_eu(4,4)) drive the allocator to 64 VGPR -> scratch
// spills (FETCH 13.6->34 MB, WRITE 26.5->56 MB) -> slower. Do not force.
// R8 lesson: do NOT split this grid along columns — A-traffic multiplies.
// ---------------------------------------------------------------------------
#define MMG(AF, ACC, BASE)                                                    \
    _Pragma("unroll")                                                         \
    for (int tc = 0; tc < 8; tc++) {                                          \
        bhalf8 bfr[4];                                                        \
        _Pragma("unroll")                                                     \
        for (int kb = 0; kb < 4; kb++)                                        \
            bfr[kb] = *(const bhalf8*)&(BASE)[((tc * 4 + kb) * 64 + lane) * 8]; \
        _Pragma("unroll")                                                     \
        for (int kb = 0; kb < 4; kb++)                                        \
            ACC[tc] = __builtin_amdgcn_mfma_f32_16x16x32_bf16(AF[kb], bfr[kb], ACC[tc], 0, 0, 0); \
    }

__global__ __launch_bounds__(256) void k_gru(
    const unsigned short* __restrict__ aggxb, const float* __restrict__ sumatt,
    const unsigned short* __restrict__ xb,
    const unsigned short* __restrict__ wcb, const float* __restrict__ bmih,
    const float* __restrict__ bih,
    const unsigned short* __restrict__ whhb, const float* __restrict__ bhh,
    float* __restrict__ y, double* __restrict__ bnsum)
{
    __shared__ __align__(16) float hst[64 * 128];   // 32 KB h staging
    const int t = threadIdx.x;
    const int wave = t >> 6, lane = t & 63;
    const int col = lane & 15, quad = (lane >> 4) & 3;
    const int node0 = blockIdx.x * 64;

    const int anode = node0 + wave * 16 + col;
    bhalf8 afA[4], afX[4];
#pragma unroll
    for (int kb = 0; kb < 4; kb++) {
        afA[kb] = *(const bhalf8*)&aggxb[(size_t)anode * HID + kb * 32 + quad * 8];
        afX[kb] = *(const bhalf8*)&xb[(size_t)anode * HID + kb * 32 + quad * 8];
    }
    float sa[4];
#pragma unroll
    for (int e = 0; e < 4; e++) sa[e] = sumatt[node0 + wave * 16 + quad * 4 + e];

    floatx4 accR[8], accN[8];

    // ===== gate r: merged accumulator (gi+gh) =====
#pragma unroll
    for (int tc = 0; tc < 8; tc++) {
        int f = 0 * 128 + tc * 16 + col;
        float b0 = bih[f] + bhh[f], bm = bmih[f];
        accR[tc] = (floatx4){b0 + sa[0] * bm, b0 + sa[1] * bm, b0 + sa[2] * bm, b0 + sa[3] * bm};
    }
    MMG(afA, accR, wcb + 0 * 16384);
    MMG(afX, accR, whhb + 0 * 16384);
#pragma unroll
    for (int tc = 0; tc < 8; tc++)
#pragma unroll
        for (int e = 0; e < 4; e++)
            accR[tc][e] = sigm(accR[tc][e]);          // accR now holds r

    // ===== gate n: acc = afX@Whh + bh; acc = r*acc + bi + sa*bm; acc += afA@Wc =====
#pragma unroll
    for (int tc = 0; tc < 8; tc++) {
        float bh = bhh[2 * 128 + tc * 16 + col];
        accN[tc] = (floatx4){bh, bh, bh, bh};
    }
    MMG(afX, accN, whhb + 2 * 16384);
#pragma unroll
    for (int tc = 0; tc < 8; tc++) {
        int f = 2 * 128 + tc * 16 + col;
        float bi = bih[f], bm = bmih[f];
#pragma unroll
        for (int e = 0; e < 4; e++)
            accN[tc][e] = accR[tc][e] * accN[tc][e] + bi + sa[e] * bm;
    }
    MMG(afA, accN, wcb + 2 * 16384);
#pragma unroll
    for (int tc = 0; tc < 8; tc++)
#pragma unroll
        for (int e = 0; e < 4; e++)
            accN[tc][e] = tanh_f(accN[tc][e]);        // accN now holds n

    // ===== gate z: merged accumulator (reuse accR) =====
#pragma unroll
    for (int tc = 0; tc < 8; tc++) {
        int f = 1 * 128 + tc * 16 + col;
        float b0 = bih[f] + bhh[f], bm = bmih[f];
        accR[tc] = (floatx4){b0 + sa[0] * bm, b0 + sa[1] * bm, b0 + sa[2] * bm, b0 + sa[3] * bm};
    }
    MMG(afA, accR, wcb + 1 * 16384);
    MMG(afX, accR, whhb + 1 * 16384);

    // ===== h = (1-z)*n + z*x, stage, write, BN sums =====
#pragma unroll
    for (int tc = 0; tc < 8; tc++) {
#pragma unroll
        for (int e = 0; e < 4; e++) {
            float z = sigm(accR[tc][e]);
            int nd = node0 + wave * 16 + quad * 4 + e;
            float xv = bf2f(xb[(size_t)nd * HID + tc * 16 + col]);
            float h = (1.0f - z) * accN[tc][e] + z * xv;
            hst[(wave * 16 + quad * 4 + e) * 128 + tc * 16 + col] = h;
        }
    }
    __syncthreads();

#pragma unroll
    for (int i = 0; i < 32; i++) {
        int idx = t + i * 256;
        if (node0 + (idx >> 7) < NN) y[(size_t)node0 * HID + idx] = hst[idx];
    }
    if (t < 128) {
        int count = NN - node0; if (count > 64) count = 64;
        float s = 0.f, s2 = 0.f;
        for (int m = 0; m < count; m++) { float v = hst[m * 128 + t]; s += v; s2 += v * v; }
        unsafeAtomicAdd(&bnsum[t], (double)s);
        unsafeAtomicAdd(&bnsum[128 + t], (double)s2);
    }
}

// ---------------------------------------------------------------------------
// Segmented sum-pool over bf16 xb (batch_idx is SORTED)
// ---------------------------------------------------------------------------
__global__ __launch_bounds__(256) void k_pool(
    const unsigned short* __restrict__ xb, const int* __restrict__ batch,
    float* __restrict__ gr)
{
    __shared__ int sb[256];
    const int t = threadIdx.x;
    const int nb = blockIdx.x * 256;
    int ld = nb + t; if (ld >= NN) ld = NN - 1;
    sb[t] = batch[ld];
    __syncthreads();
    const int s = t >> 7, f = t & 127;
    float acc = 0.f; int cur = -1;
    for (int i = s; i < 256; i += 2) {
        int n = nb + i;
        if (n >= NN) break;
        int g = sb[i];
        if (g != cur) {
            if (cur >= 0) unsafeAtomicAdd(&gr[(size_t)cur * HID + f], acc);
            acc = 0.f; cur = g;
        }
        acc += bf2f(xb[(size_t)n * HID + f]);
    }
    if (cur >= 0) unsafeAtomicAdd(&gr[(size_t)cur * HID + f], acc);
}

// ---------------------------------------------------------------------------
// Readout: out[g] = relu(gr[g] @ W1^T + b1) @ W2^T + b2   (128 blocks x 64)
// ---------------------------------------------------------------------------
__global__ __launch_bounds__(64) void k_readout(
    const float* __restrict__ gr, const float* __restrict__ W1,
    const float* __restrict__ b1, const float* __restrict__ W2,
    const float* __restrict__ b2, float* __restrict__ out)
{
    const int g = blockIdx.x, j = threadIdx.x;
    float acc = b1[j];
    const float4* grow = (const float4*)&gr[g * HID];
    const float4* wrow = (const float4*)&W1[j * HID];
#pragma unroll
    for (int k4 = 0; k4 < 32; k4++) {
        float4 a = grow[k4], w = wrow[k4];
        acc += a.x * w.x + a.y * w.y + a.z * w.z + a.w * w.w;
    }
    float h = fmaxf(acc, 0.0f) * W2[j];
#pragma unroll
    for (int msk = 32; msk >= 1; msk >>= 1) h += __shfl_xor(h, msk);
    if (j == 0) out[g] = h + b2[0];
}

// ---------------------------------------------------------------------------
extern "C" void kernel_launch(void* const* d_in, const int* in_sizes, int n_in,
                              void* d_out, int out_size, void* d_ws, size_t ws_size,
                              hipStream_t stream)
{
    const float* nf    = (const float*)d_in[0];
    const int*   ei    = (const int*)d_in[1];
    const int*   batch = (const int*)d_in[2];
    const float* embW  = (const float*)d_in[3];
    const float* embb  = (const float*)d_in[4];
    const float* embg  = (const float*)d_in[5];
    const float* embbe = (const float*)d_in[6];
    const float* msgW  = (const float*)d_in[7];
    const float* msgb  = (const float*)d_in[8];
    const float* attW  = (const float*)d_in[9];
    const float* attb  = (const float*)d_in[10];
    const float* Wih   = (const float*)d_in[11];
    const float* bih   = (const float*)d_in[12];
    const float* Whh   = (const float*)d_in[13];
    const float* bhh   = (const float*)d_in[14];
    const float* bng   = (const float*)d_in[15];
    const float* bnb   = (const float*)d_in[16];
    const float* roW1  = (const float*)d_in[17];
    const float* rob1  = (const float*)d_in[18];
    const float* roW2  = (const float*)d_in[19];
    const float* rob2  = (const float*)d_in[20];
    const int* src = ei;
    const int* dst = ei + NE;
    float* out = (float*)d_out;

    // ---- workspace layout (all sections 16B-multiple) ----
    char* base = (char*)d_ws;
    const size_t NH = (size_t)NN * HID;      // 6.4M elements
    double* bnsum = (double*)base;           // 256 doubles = 2048 B
    float* y     = (float*)(base + 2048);    // pre-BN state
    unsigned short* xb    = (unsigned short*)(y + NH);   // bf16 node state
    unsigned short* aggxb = xb + NH;                     // bf16 gather output
    float* as_   = (float*)(aggxb + NH);
    float* ad_   = as_ + NN;
    float* sumatt= ad_ + NN;
    float* ss    = sumatt + NN;              // 256: scale|shift
    float* gr    = ss + 256;                 // 128*128
    float* Wc    = gr + NGRAPHS * HID;       // 4*384*128 fp32
    float* bmih  = Wc + 4 * 384 * 128;       // 4*384
    int* rowptr  = (int*)(bmih + 4 * 384);   // NN+4 (padded for alignment)
    int* wptr    = rowptr + NN + 4;          // NN
    int* cnt     = wptr + NN;                // NN
    int* bsum    = cnt + NN;                 // 128 (scan block totals)
    int* ssrc    = bsum + 128;               // NE
    unsigned short* wcb  = (unsigned short*)(ssrc + NE); // 4*49152 bf16 frags
    unsigned short* whhb = wcb + 4 * 49152;              // 4*49152 bf16 frags
    unsigned short* nfb  = whhb + 4 * 49152;             // NNP*96 bf16 padded nf
    unsigned short* web  = nfb + (size_t)NNP * 96;       // 12288 emb B-frags

    // ---- once-per-call precompute: weights (+bf16 frags), nf cast, CSR ----
    k_wc<<<4 * 384, 128, 0, stream>>>(Wih, msgW, msgb, Wc, bmih);
    k_frag<<<8 * 192, 256, 0, stream>>>(Wc, Whh, wcb, whhb);
    k_nfb<<<(NN * 24 + 255) / 256, 256, 0, stream>>>(nf, nfb);
    k_wfrag_emb<<<48, 256, 0, stream>>>(embW, web);
    hipMemsetAsync(cnt, 0, NN * sizeof(int), stream);
    k_count<<<(NE + 255) / 256, 256, 0, stream>>>(dst, cnt);
    k_scan1<<<SCAN_G, SCAN_B, 0, stream>>>(cnt, rowptr, bsum);
    k_scan2<<<1, 128, 0, stream>>>(bsum, rowptr);
    k_scan3<<<SCAN_G, SCAN_B, 0, stream>>>(rowptr, bsum, wptr);
    k_scatter<<<(NE + 255) / 256, 256, 0, stream>>>(src, dst, wptr, ssrc);

    // ---- MFMA embedding + BN + att-proj for layer 0 ----
    hipMemsetAsync(bnsum, 0, 256 * sizeof(double), stream);
    k_embed_m<<<NB64, 256, 0, stream>>>(nfb, web, embb, y, bnsum);
    k_bnfin<<<1, 128, 0, stream>>>(bnsum, embg, embbe, ss);   // also re-zeros bnsum
    k_bnx<<<NN / 4, 256, 0, stream>>>(y, ss, attW, xb, as_, ad_);

    for (int l = 0; l < NLAYERS; l++) {
        k_gather<<<NN / 8, 256, 0, stream>>>(rowptr, ssrc, xb, as_, ad_, attb, l, aggxb, sumatt);
        k_gru<<<NB64, 256, 0, stream>>>(
            aggxb, sumatt, xb,
            wcb + (size_t)l * 49152, bmih + (size_t)l * 384, bih + (size_t)l * 384,
            whhb + (size_t)l * 49152, bhh + (size_t)l * 384, y, bnsum);
        k_bnfin<<<1, 128, 0, stream>>>(bnsum, bng + (size_t)l * HID, bnb + (size_t)l * HID, ss);
        const float* attW_next = attW + (size_t)((l + 1 < NLAYERS) ? l + 1 : l) * 256;
        k_bnx<<<NN / 4, 256, 0, stream>>>(y, ss, attW_next, xb, as_, ad_);
    }

    hipMemsetAsync(gr, 0, NGRAPHS * HID * sizeof(float), stream);
    k_pool<<<(NN + 255) / 256, 256, 0, stream>>>(xb, batch, gr);
    k_readout<<<NGRAPHS, 64, 0, stream>>>(gr, roW1, rob1, roW2, rob2, out);
}

// Round 15
// 695.205 us; speedup vs baseline: 1.0765x; 1.0021x over previous
//
#include <hip/hip_runtime.h>
#include <math.h>

#define NN 50000
#define NE 600000
#define ADIM 75
#define HID 128
#define NLAYERS 4
#define NGRAPHS 128
#define BN_EPS 1e-5f
#define NNP 50048   // NN padded to 64-node blocks
#define NB64 (NNP / 64)   // 782 node-blocks

typedef short bhalf8 __attribute__((ext_vector_type(8)));
typedef float floatx4 __attribute__((ext_vector_type(4)));

__device__ __forceinline__ float sigm(float v) { return 1.0f / (1.0f + __expf(-v)); }
__device__ __forceinline__ float tanh_f(float v) {
    return 1.0f - 2.0f / (__expf(2.0f * v) + 1.0f);
}

// fp32 -> bf16 with round-to-nearest-even
__device__ __forceinline__ unsigned short f2bf(float f) {
    unsigned u = __builtin_bit_cast(unsigned, f);
    u = (u + 0x7FFFu + ((u >> 16) & 1u)) >> 16;
    return (unsigned short)u;
}
__device__ __forceinline__ float bf2f(unsigned short h) {
    return __builtin_bit_cast(float, ((unsigned)h) << 16);
}

// ---------------------------------------------------------------------------
// nf [NN x 75] fp32 -> nfb [NNP x 96] bf16 (K zero-padded 75->96)
// ---------------------------------------------------------------------------
__global__ __launch_bounds__(256) void k_nfb(
    const float* __restrict__ nf, unsigned short* __restrict__ nfb)
{
    int e = blockIdx.x * 256 + threadIdx.x;      // (n, k4): 50000*24
    if (e >= NN * 24) return;
    int n = e / 24, k4 = e - n * 24;
    ushort4 o;
    int k = k4 * 4;
    o.x = (k + 0 < ADIM) ? f2bf(nf[(size_t)n * ADIM + k + 0]) : 0;
    o.y = (k + 1 < ADIM) ? f2bf(nf[(size_t)n * ADIM + k + 1]) : 0;
    o.z = (k + 2 < ADIM) ? f2bf(nf[(size_t)n * ADIM + k + 2]) : 0;
    o.w = (k + 3 < ADIM) ? f2bf(nf[(size_t)n * ADIM + k + 3]) : 0;
    ((ushort4*)nfb)[(size_t)n * 24 + k4] = o;
}

// ---------------------------------------------------------------------------
// embW [128 x 75] -> bf16 B-fragments, K padded to 96:
//   layout [tc(8)][kb(3)][quad(4)][n(16)][j(8)], elem = W[tc*16+n][kb*32+quad*8+j]
// ---------------------------------------------------------------------------
__global__ __launch_bounds__(256) void k_wfrag_emb(
    const float* __restrict__ W, unsigned short* __restrict__ web)
{
    int e = blockIdx.x * 256 + threadIdx.x;      // 0..12287
    int j = e & 7, n = (e >> 3) & 15, quad = (e >> 7) & 3;
    int kb = (e >> 9) % 3, tc = e / 1536;
    int row = tc * 16 + n;
    int kk = kb * 32 + quad * 8 + j;
    web[e] = (kk < ADIM) ? f2bf(W[row * ADIM + kk]) : 0;
}

// ---------------------------------------------------------------------------
// MFMA embedding: y = relu(nf @ embW^T + b), BN sums into slot 0.
// block 256 = 4 waves x 16 nodes (64 nodes/block); grid 782.
// ---------------------------------------------------------------------------
__global__ __launch_bounds__(256) void k_embed_m(
    const unsigned short* __restrict__ nfb, const unsigned short* __restrict__ web,
    const float* __restrict__ b, float* __restrict__ y,
    double* __restrict__ bnsum)
{
    __shared__ __align__(16) float hst[64 * 128];   // 32 KB h staging
    const int t = threadIdx.x;
    const int wave = t >> 6, lane = t & 63;
    const int col = lane & 15, quad = (lane >> 4) & 3;
    const int node0 = blockIdx.x * 64;

    const int anode = node0 + wave * 16 + col;
    bhalf8 afN[3];
#pragma unroll
    for (int kb = 0; kb < 3; kb++)
        afN[kb] = *(const bhalf8*)&nfb[(size_t)anode * 96 + kb * 32 + quad * 8];

    floatx4 acc[8];
#pragma unroll
    for (int tc = 0; tc < 8; tc++) {
        float bv = b[tc * 16 + col];
        acc[tc] = (floatx4){bv, bv, bv, bv};
    }

#pragma unroll
    for (int tc = 0; tc < 8; tc++) {
        bhalf8 bfr[3];
#pragma unroll
        for (int kb = 0; kb < 3; kb++)
            bfr[kb] = *(const bhalf8*)&web[((tc * 3 + kb) * 64 + lane) * 8];
#pragma unroll
        for (int kb = 0; kb < 3; kb++)
            acc[tc] = __builtin_amdgcn_mfma_f32_16x16x32_bf16(afN[kb], bfr[kb], acc[tc], 0, 0, 0);
    }

#pragma unroll
    for (int tc = 0; tc < 8; tc++)
#pragma unroll
        for (int e = 0; e < 4; e++) {
            float v = fmaxf(acc[tc][e], 0.0f);
            hst[(wave * 16 + quad * 4 + e) * 128 + tc * 16 + col] = v;
        }
    __syncthreads();

#pragma unroll
    for (int i = 0; i < 32; i++) {
        int idx = t + i * 256;
        if (node0 + (idx >> 7) < NN) y[(size_t)node0 * HID + idx] = hst[idx];
    }
    if (t < 128) {
        int count = NN - node0; if (count > 64) count = 64;
        float s = 0.f, s2 = 0.f;
        for (int m = 0; m < count; m++) { float v = hst[m * 128 + t]; s += v; s2 += v * v; }
        unsafeAtomicAdd(&bnsum[t], (double)s);
        unsafeAtomicAdd(&bnsum[128 + t], (double)s2);
    }
}

// ---------------------------------------------------------------------------
// Fused BN-finalize + BN-apply + bf16 mirror + attention projections.
// R15: k_bnfin deleted — each block derives scale/shift from the per-layer
// bnsum slot (4 double loads + rsqrt per thread; slot zeroed once upfront).
// ---------------------------------------------------------------------------
__global__ __launch_bounds__(256) void k_bnx(
    const float* __restrict__ y, const double* __restrict__ bnsum,
    const float* __restrict__ g, const float* __restrict__ beta,
    const float* __restrict__ attW,
    unsigned short* __restrict__ xb,
    float* __restrict__ as_, float* __restrict__ ad_)
{
    const int t = threadIdx.x;
    const int n = blockIdx.x * 4 + (t >> 6);
    const int lane = t & 63;
    const int f0 = lane * 2;
    // per-thread BN scale/shift for features f0, f0+1
    double m0 = bnsum[f0] / (double)NN;
    double v0 = bnsum[128 + f0] / (double)NN - m0 * m0;
    double m1 = bnsum[f0 + 1] / (double)NN;
    double v1 = bnsum[128 + f0 + 1] / (double)NN - m1 * m1;
    float sc0 = g[f0] * rsqrtf((float)v0 + BN_EPS);
    float sc1 = g[f0 + 1] * rsqrtf((float)v1 + BN_EPS);
    float sh0 = beta[f0] - (float)m0 * sc0;
    float sh1 = beta[f0 + 1] - (float)m1 * sc1;

    float2 v = ((const float2*)y)[(size_t)n * 64 + lane];
    float2 xv;
    xv.x = v.x * sc0 + sh0;
    xv.y = v.y * sc1 + sh1;
    unsigned pk = (unsigned)f2bf(xv.x) | ((unsigned)f2bf(xv.y) << 16);
    ((unsigned*)xb)[(size_t)n * 64 + lane] = pk;
    float2 aws = ((const float2*)attW)[lane];
    float2 awd = ((const float2*)(attW + 128))[lane];
    float pas = xv.x * aws.x + xv.y * aws.y;
    float pad = xv.x * awd.x + xv.y * awd.y;
#pragma unroll
    for (int msk = 32; msk >= 1; msk >>= 1) {
        pas += __shfl_xor(pas, msk);
        pad += __shfl_xor(pad, msk);
    }
    if (lane == 0) { as_[n] = pas; ad_[n] = pad; }
}

// ---------------------------------------------------------------------------
// Combined-weight precompute: Wc[l] = Wih[l] @ Wm[l], bmih[l] = Wih[l] @ bm[l]
// ---------------------------------------------------------------------------
__global__ __launch_bounds__(128) void k_wc(
    const float* __restrict__ Wih, const float* __restrict__ Wm,
    const float* __restrict__ bm, float* __restrict__ Wc, float* __restrict__ bmih)
{
    __shared__ float sw[128];
    __shared__ float red[128];
    const int b = blockIdx.x;
    const int l = b / 384, r = b - l * 384;
    const int t = threadIdx.x;
    const float* wihrow = Wih + ((size_t)l * 384 + r) * 128;
    sw[t] = wihrow[t];
    __syncthreads();
    const float* wm = Wm + (size_t)l * 128 * 128;
    float acc = 0.f;
#pragma unroll 8
    for (int k = 0; k < 128; k++) acc += sw[k] * wm[k * 128 + t];
    Wc[((size_t)l * 384 + r) * 128 + t] = acc;
    red[t] = sw[t] * bm[l * 128 + t];
    __syncthreads();
#pragma unroll
    for (int off = 64; off >= 1; off >>= 1) {
        if (t < off) red[t] += red[t + off];
        __syncthreads();
    }
    if (t == 0) bmih[l * 384 + r] = red[0];
}

// ---------------------------------------------------------------------------
// Convert Wc (fp32) and Whh to bf16 in MFMA B-fragment order:
//   layout [gate(3)][tc(8)][kb(4)][quad(4)][n(16)][j(8)] per layer-matrix
// ---------------------------------------------------------------------------
__global__ __launch_bounds__(256) void k_frag(
    const float* __restrict__ Wc, const float* __restrict__ Whh,
    unsigned short* __restrict__ wcb, unsigned short* __restrict__ whhb)
{
    const int b = blockIdx.x;
    const int mat = b / 192;
    const int e = (b - mat * 192) * 256 + threadIdx.x;   // 0..49151
    const int l = mat >> 1, which = mat & 1;
    const float* src = which ? (Whh + (size_t)l * 49152) : (Wc + (size_t)l * 49152);
    unsigned short* dst = which ? (whhb + (size_t)l * 49152) : (wcb + (size_t)l * 49152);
    int j = e & 7, n = (e >> 3) & 15, quad = (e >> 7) & 3;
    int kb = (e >> 9) & 3, tc = (e >> 11) & 7, g = (e >> 14) & 3;
    int row = g * 128 + tc * 16 + n;
    int kk = kb * 32 + quad * 8 + j;
    dst[e] = f2bf(src[row * 128 + kk]);
}

// ---------------------------------------------------------------------------
// CSR build: histogram, 3-kernel device-wide scan, scatter
// ---------------------------------------------------------------------------
__global__ __launch_bounds__(256) void k_count(const int* __restrict__ dst, int* __restrict__ cnt)
{
    int e = blockIdx.x * 256 + threadIdx.x;
    if (e < NE) atomicAdd(&cnt[dst[e]], 1);
}

#define SCAN_B 512
#define SCAN_G 98          // 98*512 = 50176 >= 50000

__global__ __launch_bounds__(SCAN_B) void k_scan1(
    const int* __restrict__ cnt, int* __restrict__ rowptr, int* __restrict__ bsum)
{
    __shared__ int s[SCAN_B];
    const int t = threadIdx.x;
    const int i = blockIdx.x * SCAN_B + t;
    int v = (i < NN) ? cnt[i] : 0;
    s[t] = v;
    __syncthreads();
#pragma unroll
    for (int off = 1; off < SCAN_B; off <<= 1) {
        int u = (t >= off) ? s[t - off] : 0;
        __syncthreads();
        s[t] += u;
        __syncthreads();
    }
    if (i < NN) rowptr[i] = s[t] - v;        // local exclusive
    if (t == SCAN_B - 1) bsum[blockIdx.x] = s[t];
}

__global__ __launch_bounds__(128) void k_scan2(int* __restrict__ bsum, int* __restrict__ rowptr)
{
    __shared__ int s[128];
    const int t = threadIdx.x;
    int v = (t < SCAN_G) ? bsum[t] : 0;
    s[t] = v;
    __syncthreads();
#pragma unroll
    for (int off = 1; off < 128; off <<= 1) {
        int u = (t >= off) ? s[t - off] : 0;
        __syncthreads();
        s[t] += u;
        __syncthreads();
    }
    if (t < SCAN_G) bsum[t] = s[t] - v;      // exclusive offsets
    if (t == 127) rowptr[NN] = s[127];       // grand total (= NE)
}

__global__ __launch_bounds__(SCAN_B) void k_scan3(
    int* __restrict__ rowptr, const int* __restrict__ bsum, int* __restrict__ wptr)
{
    const int i = blockIdx.x * SCAN_B + threadIdx.x;
    if (i < NN) {
        int v = rowptr[i] + bsum[blockIdx.x];
        rowptr[i] = v;
        wptr[i] = v;
    }
}

__global__ __launch_bounds__(256) void k_scatter(
    const int* __restrict__ src, const int* __restrict__ dst,
    int* __restrict__ wptr, int* __restrict__ ssrc)
{
    int e = blockIdx.x * 256 + threadIdx.x;
    if (e < NE) {
        int d = dst[e];
        int pos = atomicAdd(&wptr[d], 1);
        ssrc[pos] = src[e];
    }
}

// ---------------------------------------------------------------------------
// Gather-aggregate, batched + id-PIPELINED (R15): prefetch batch b+1's edge
// ids while batch b's 8 row loads are in flight — ~1 exposed latency per
// batch instead of 2. block 256 = 8 nodes x 32 lanes; grid NN/8.
// ---------------------------------------------------------------------------
__global__ __launch_bounds__(256) void k_gather(
    const int* __restrict__ rowptr, const int* __restrict__ ssrc,
    const unsigned short* __restrict__ xb, const float* __restrict__ as_,
    const float* __restrict__ ad_, const float* __restrict__ attb, int l,
    unsigned short* __restrict__ aggxb, float* __restrict__ sumatt)
{
    const int t = threadIdx.x;
    const int n = blockIdx.x * 8 + (t >> 5);
    const int lane = t & 31;
    const int r0 = rowptr[n], r1 = rowptr[n + 1];
    const float adv = ad_[n] + attb[l];
    float4 acc = make_float4(0.f, 0.f, 0.f, 0.f);
    float satt = 0.f;

    int ids[8], ids2[8];
    if (r0 < r1) {
#pragma unroll
        for (int k = 0; k < 8; k++) {
            int idx = r0 + k; if (idx >= r1) idx = r1 - 1;
            ids[k] = ssrc[idx];
        }
    }
    for (int base = r0; base < r1; base += 8) {
        const int nxt = base + 8;
        if (nxt < r1) {
#pragma unroll
            for (int k = 0; k < 8; k++) {
                int idx = nxt + k; if (idx >= r1) idx = r1 - 1;
                ids2[k] = ssrc[idx];
            }
        }
        ushort4 v[8];
        float a[8];
#pragma unroll
        for (int k = 0; k < 8; k++) {
            v[k] = ((const ushort4*)xb)[(size_t)ids[k] * 32 + lane];
            a[k] = as_[ids[k]];
        }
#pragma unroll
        for (int k = 0; k < 8; k++) {
            if (base + k < r1) {
                float att = sigm(a[k] + adv);
                acc.x += bf2f(v[k].x) * att; acc.y += bf2f(v[k].y) * att;
                acc.z += bf2f(v[k].z) * att; acc.w += bf2f(v[k].w) * att;
                satt += att;
            }
        }
#pragma unroll
        for (int k = 0; k < 8; k++) ids[k] = ids2[k];
    }
    ushort4 o;
    o.x = f2bf(acc.x); o.y = f2bf(acc.y); o.z = f2bf(acc.z); o.w = f2bf(acc.w);
    ((ushort4*)aggxb)[(size_t)n * 32 + lane] = o;
    if (lane == 0) sumatt[n] = satt;
}

// ---------------------------------------------------------------------------
// MFMA GRU, barrier-free K-loop, register-slim algebra (R12 best config).
// Plain launch_bounds(256): natural allocation 136 VGPR, no spills, 69 us.
// R11/R13 lesson: BOTH occupancy forcings (launch_bounds(256,4) and
// amdgpu_waves_per_eu(4,4)) drive the allocator to 64 VGPR -> scratch
// spills (FETCH 13.6->34 MB, WRITE 26.5->56 MB) -> slower. Do not force.
// R8 lesson: do NOT split this grid along columns — A-traffic multiplies.
// ---------------------------------------------------------------------------
#define MMG(AF, ACC, BASE)                                                    \
    _Pragma("unroll")                                                         \
    for (int tc = 0; tc < 8; tc++) {                                          \
        bhalf8 bfr[4];                                                        \
        _Pragma("unroll")                                                     \
        for (int kb = 0; kb < 4; kb++)                                        \
            bfr[kb] = *(const bhalf8*)&(BASE)[((tc * 4 + kb) * 64 + lane) * 8]; \
        _Pragma("unroll")                                                     \
        for (int kb = 0; kb < 4; kb++)                                        \
            ACC[tc] = __builtin_amdgcn_mfma_f32_16x16x32_bf16(AF[kb], bfr[kb], ACC[tc], 0, 0, 0); \
    }

__global__ __launch_bounds__(256) void k_gru(
    const unsigned short* __restrict__ aggxb, const float* __restrict__ sumatt,
    const unsigned short* __restrict__ xb,
    const unsigned short* __restrict__ wcb, const float* __restrict__ bmih,
    const float* __restrict__ bih,
    const unsigned short* __restrict__ whhb, const float* __restrict__ bhh,
    float* __restrict__ y, double* __restrict__ bnsum)
{
    __shared__ __align__(16) float hst[64 * 128];   // 32 KB h staging
    const int t = threadIdx.x;
    const int wave = t >> 6, lane = t & 63;
    const int col = lane & 15, quad = (lane >> 4) & 3;
    const int node0 = blockIdx.x * 64;

    const int anode = node0 + wave * 16 + col;
    bhalf8 afA[4], afX[4];
#pragma unroll
    for (int kb = 0; kb < 4; kb++) {
        afA[kb] = *(const bhalf8*)&aggxb[(size_t)anode * HID + kb * 32 + quad * 8];
        afX[kb] = *(const bhalf8*)&xb[(size_t)anode * HID + kb * 32 + quad * 8];
    }
    float sa[4];
#pragma unroll
    for (int e = 0; e < 4; e++) sa[e] = sumatt[node0 + wave * 16 + quad * 4 + e];

    floatx4 accR[8], accN[8];

    // ===== gate r: merged accumulator (gi+gh) =====
#pragma unroll
    for (int tc = 0; tc < 8; tc++) {
        int f = 0 * 128 + tc * 16 + col;
        float b0 = bih[f] + bhh[f], bm = bmih[f];
        accR[tc] = (floatx4){b0 + sa[0] * bm, b0 + sa[1] * bm, b0 + sa[2] * bm, b0 + sa[3] * bm};
    }
    MMG(afA, accR, wcb + 0 * 16384);
    MMG(afX, accR, whhb + 0 * 16384);
#pragma unroll
    for (int tc = 0; tc < 8; tc++)
#pragma unroll
        for (int e = 0; e < 4; e++)
            accR[tc][e] = sigm(accR[tc][e]);          // accR now holds r

    // ===== gate n: acc = afX@Whh + bh; acc = r*acc + bi + sa*bm; acc += afA@Wc =====
#pragma unroll
    for (int tc = 0; tc < 8; tc++) {
        float bh = bhh[2 * 128 + tc * 16 + col];
        accN[tc] = (floatx4){bh, bh, bh, bh};
    }
    MMG(afX, accN, whhb + 2 * 16384);
#pragma unroll
    for (int tc = 0; tc < 8; tc++) {
        int f = 2 * 128 + tc * 16 + col;
        float bi = bih[f], bm = bmih[f];
#pragma unroll
        for (int e = 0; e < 4; e++)
            accN[tc][e] = accR[tc][e] * accN[tc][e] + bi + sa[e] * bm;
    }
    MMG(afA, accN, wcb + 2 * 16384);
#pragma unroll
    for (int tc = 0; tc < 8; tc++)
#pragma unroll
        for (int e = 0; e < 4; e++)
            accN[tc][e] = tanh_f(accN[tc][e]);        // accN now holds n

    // ===== gate z: merged accumulator (reuse accR) =====
#pragma unroll
    for (int tc = 0; tc < 8; tc++) {
        int f = 1 * 128 + tc * 16 + col;
        float b0 = bih[f] + bhh[f], bm = bmih[f];
        accR[tc] = (floatx4){b0 + sa[0] * bm, b0 + sa[1] * bm, b0 + sa[2] * bm, b0 + sa[3] * bm};
    }
    MMG(afA, accR, wcb + 1 * 16384);
    MMG(afX, accR, whhb + 1 * 16384);

    // ===== h = (1-z)*n + z*x, stage, write, BN sums =====
#pragma unroll
    for (int tc = 0; tc < 8; tc++) {
#pragma unroll
        for (int e = 0; e < 4; e++) {
            float z = sigm(accR[tc][e]);
            int nd = node0 + wave * 16 + quad * 4 + e;
            float xv = bf2f(xb[(size_t)nd * HID + tc * 16 + col]);
            float h = (1.0f - z) * accN[tc][e] + z * xv;
            hst[(wave * 16 + quad * 4 + e) * 128 + tc * 16 + col] = h;
        }
    }
    __syncthreads();

#pragma unroll
    for (int i = 0; i < 32; i++) {
        int idx = t + i * 256;
        if (node0 + (idx >> 7) < NN) y[(size_t)node0 * HID + idx] = hst[idx];
    }
    if (t < 128) {
        int count = NN - node0; if (count > 64) count = 64;
        float s = 0.f, s2 = 0.f;
        for (int m = 0; m < count; m++) { float v = hst[m * 128 + t]; s += v; s2 += v * v; }
        unsafeAtomicAdd(&bnsum[t], (double)s);
        unsafeAtomicAdd(&bnsum[128 + t], (double)s2);
    }
}

// ---------------------------------------------------------------------------
// Segmented sum-pool over bf16 xb (batch_idx is SORTED)
// ---------------------------------------------------------------------------
__global__ __launch_bounds__(256) void k_pool(
    const unsigned short* __restrict__ xb, const int* __restrict__ batch,
    float* __restrict__ gr)
{
    __shared__ int sb[256];
    const int t = threadIdx.x;
    const int nb = blockIdx.x * 256;
    int ld = nb + t; if (ld >= NN) ld = NN - 1;
    sb[t] = batch[ld];
    __syncthreads();
    const int s = t >> 7, f = t & 127;
    float acc = 0.f; int cur = -1;
    for (int i = s; i < 256; i += 2) {
        int n = nb + i;
        if (n >= NN) break;
        int g = sb[i];
        if (g != cur) {
            if (cur >= 0) unsafeAtomicAdd(&gr[(size_t)cur * HID + f], acc);
            acc = 0.f; cur = g;
        }
        acc += bf2f(xb[(size_t)n * HID + f]);
    }
    if (cur >= 0) unsafeAtomicAdd(&gr[(size_t)cur * HID + f], acc);
}

// ---------------------------------------------------------------------------
// Readout: out[g] = relu(gr[g] @ W1^T + b1) @ W2^T + b2   (128 blocks x 64)
// ---------------------------------------------------------------------------
__global__ __launch_bounds__(64) void k_readout(
    const float* __restrict__ gr, const float* __restrict__ W1,
    const float* __restrict__ b1, const float* __restrict__ W2,
    const float* __restrict__ b2, float* __restrict__ out)
{
    const int g = blockIdx.x, j = threadIdx.x;
    float acc = b1[j];
    const float4* grow = (const float4*)&gr[g * HID];
    const float4* wrow = (const float4*)&W1[j * HID];
#pragma unroll
    for (int k4 = 0; k4 < 32; k4++) {
        float4 a = grow[k4], w = wrow[k4];
        acc += a.x * w.x + a.y * w.y + a.z * w.z + a.w * w.w;
    }
    float h = fmaxf(acc, 0.0f) * W2[j];
#pragma unroll
    for (int msk = 32; msk >= 1; msk >>= 1) h += __shfl_xor(h, msk);
    if (j == 0) out[g] = h + b2[0];
}

// ---------------------------------------------------------------------------
extern "C" void kernel_launch(void* const* d_in, const int* in_sizes, int n_in,
                              void* d_out, int out_size, void* d_ws, size_t ws_size,
                              hipStream_t stream)
{
    const float* nf    = (const float*)d_in[0];
    const int*   ei    = (const int*)d_in[1];
    const int*   batch = (const int*)d_in[2];
    const float* embW  = (const float*)d_in[3];
    const float* embb  = (const float*)d_in[4];
    const float* embg  = (const float*)d_in[5];
    const float* embbe = (const float*)d_in[6];
    const float* msgW  = (const float*)d_in[7];
    const float* msgb  = (const float*)d_in[8];
    const float* attW  = (const float*)d_in[9];
    const float* attb  = (const float*)d_in[10];
    const float* Wih   = (const float*)d_in[11];
    const float* bih   = (const float*)d_in[12];
    const float* Whh   = (const float*)d_in[13];
    const float* bhh   = (const float*)d_in[14];
    const float* bng   = (const float*)d_in[15];
    const float* bnb   = (const float*)d_in[16];
    const float* roW1  = (const float*)d_in[17];
    const float* rob1  = (const float*)d_in[18];
    const float* roW2  = (const float*)d_in[19];
    const float* rob2  = (const float*)d_in[20];
    const int* src = ei;
    const int* dst = ei + NE;
    float* out = (float*)d_out;

    // ---- workspace layout (all sections 16B-multiple) ----
    char* base = (char*)d_ws;
    const size_t NH = (size_t)NN * HID;      // 6.4M elements
    double* bnsum = (double*)base;           // 5 slots x 256 doubles = 10240 B
    float* y     = (float*)(base + 10240);   // pre-BN state
    unsigned short* xb    = (unsigned short*)(y + NH);   // bf16 node state
    unsigned short* aggxb = xb + NH;                     // bf16 gather output
    float* as_   = (float*)(aggxb + NH);
    float* ad_   = as_ + NN;
    float* sumatt= ad_ + NN;
    float* gr    = sumatt + NN;              // 128*128
    float* Wc    = gr + NGRAPHS * HID;       // 4*384*128 fp32
    float* bmih  = Wc + 4 * 384 * 128;       // 4*384
    int* rowptr  = (int*)(bmih + 4 * 384);   // NN+4 (padded for alignment)
    int* wptr    = rowptr + NN + 4;          // NN
    int* cnt     = wptr + NN;                // NN
    int* bsum    = cnt + NN;                 // 128 (scan block totals)
    int* ssrc    = bsum + 128;               // NE
    unsigned short* wcb  = (unsigned short*)(ssrc + NE); // 4*49152 bf16 frags
    unsigned short* whhb = wcb + 4 * 49152;              // 4*49152 bf16 frags
    unsigned short* nfb  = whhb + 4 * 49152;             // NNP*96 bf16 padded nf
    unsigned short* web  = nfb + (size_t)NNP * 96;       // 12288 emb B-frags

    // ---- once-per-call precompute: weights (+bf16 frags), nf cast, CSR ----
    k_wc<<<4 * 384, 128, 0, stream>>>(Wih, msgW, msgb, Wc, bmih);
    k_frag<<<8 * 192, 256, 0, stream>>>(Wc, Whh, wcb, whhb);
    k_nfb<<<(NN * 24 + 255) / 256, 256, 0, stream>>>(nf, nfb);
    k_wfrag_emb<<<48, 256, 0, stream>>>(embW, web);
    hipMemsetAsync(cnt, 0, NN * sizeof(int), stream);
    hipMemsetAsync(bnsum, 0, 5 * 256 * sizeof(double), stream);
    k_count<<<(NE + 255) / 256, 256, 0, stream>>>(dst, cnt);
    k_scan1<<<SCAN_G, SCAN_B, 0, stream>>>(cnt, rowptr, bsum);
    k_scan2<<<1, 128, 0, stream>>>(bsum, rowptr);
    k_scan3<<<SCAN_G, SCAN_B, 0, stream>>>(rowptr, bsum, wptr);
    k_scatter<<<(NE + 255) / 256, 256, 0, stream>>>(src, dst, wptr, ssrc);

    // ---- MFMA embedding (BN sums -> slot 0) + fused BN/att-proj ----
    k_embed_m<<<NB64, 256, 0, stream>>>(nfb, web, embb, y, bnsum);
    k_bnx<<<NN / 4, 256, 0, stream>>>(y, bnsum, embg, embbe, attW, xb, as_, ad_);

    for (int l = 0; l < NLAYERS; l++) {
        k_gather<<<NN / 8, 256, 0, stream>>>(rowptr, ssrc, xb, as_, ad_, attb, l, aggxb, sumatt);
        k_gru<<<NB64, 256, 0, stream>>>(
            aggxb, sumatt, xb,
            wcb + (size_t)l * 49152, bmih + (size_t)l * 384, bih + (size_t)l * 384,
            whhb + (size_t)l * 49152, bhh + (size_t)l * 384, y, bnsum + (l + 1) * 256);
        const float* attW_next = attW + (size_t)((l + 1 < NLAYERS) ? l + 1 : l) * 256;
        k_bnx<<<NN / 4, 256, 0, stream>>>(y, bnsum + (l + 1) * 256,
                                          bng + (size_t)l * HID, bnb + (size_t)l * HID,
                                          attW_next, xb, as_, ad_);
    }

    hipMemsetAsync(gr, 0, NGRAPHS * HID * sizeof(float), stream);
    k_pool<<<(NN + 255) / 256, 256, 0, stream>>>(xb, batch, gr);
    k_readout<<<NGRAPHS, 64, 0, stream>>>(gr, roW1, rob1, roW2, rob2, out);
}